// Round 4
// baseline (962.261 us; speedup 1.0000x reference)
//
#include <hip/hip_runtime.h>
#include <hip/hip_bf16.h>
#include <math.h>

// Problem constants (from reference)
#define RESV 128
#define V3 (RESV*RESV*RESV)          // 2097152 voxels per channel
#define N_RAYS 1024
#define N_SAMPLES 891                // int(257*sqrt(3)/0.5)+1
#define STEP_T 0.0078125f            // STEPSIZE * VOXEL = 0.5 * (2/128)
#define ACT_SHIFT -4.595119850134589f // log(1/(1-0.01) - 1)

// ---------------------------------------------------------------------------
// Kernel A: 3-channel 5x5x5 cross-correlation (zero pad 2) over density
// channel, then per-voxel negate+normalize. Output SoA: 3 planes of V3.
// ---------------------------------------------------------------------------
__global__ __launch_bounds__(256)
void normals_conv_kernel(const float* __restrict__ grid,
                         const float* __restrict__ sobel,
                         float* __restrict__ nout) {
    __shared__ float sk[375];
    const int t = threadIdx.x;
    for (int i = t; i < 375; i += 256) sk[i] = sobel[i];
    __syncthreads();

    const int gid = blockIdx.x * 256 + t;      // 0 .. V3-1
    const int iz = gid & 127;
    const int iy = (gid >> 7) & 127;
    const int ix = gid >> 14;

    float c0 = 0.f, c1 = 0.f, c2 = 0.f;
    #pragma unroll
    for (int da = -2; da <= 2; ++da) {
        int a = ix + da;
        if ((unsigned)a >= 128u) continue;       // wave-uniform
        #pragma unroll
        for (int db = -2; db <= 2; ++db) {
            int b = iy + db;
            if ((unsigned)b >= 128u) continue;   // wave-uniform
            const float* row = grid + (a * 128 + b) * 128;
            const float* k0  = sk + ((da + 2) * 5 + (db + 2)) * 5;
            #pragma unroll
            for (int dc = -2; dc <= 2; ++dc) {
                int c = iz + dc;
                int cc = min(max(c, 0), 127);
                float g = row[cc];
                g = ((unsigned)c < 128u) ? g : 0.f;
                c0 = fmaf(g, k0[dc + 2],       c0);
                c1 = fmaf(g, k0[125 + dc + 2], c1);
                c2 = fmaf(g, k0[250 + dc + 2], c2);
            }
        }
    }
    float l   = sqrtf(c0 * c0 + c1 * c1 + c2 * c2);
    float inv = -1.0f / fmaxf(l, 1e-12f);   // nrm = -nrm / max(||nrm||,1e-12)
    nout[0 * V3 + gid] = c0 * inv;
    nout[1 * V3 + gid] = c1 * inv;
    nout[2 * V3 + gid] = c2 * inv;
}

// ---------------------------------------------------------------------------
// MLP layer: register in[] -> register out[], weights broadcast from LDS as
// float4 (wave-uniform ds_read_b128). 4 independent accumulator chains.
// ---------------------------------------------------------------------------
template <int K>
__device__ __forceinline__ void layer_regs(const float* __restrict__ in,
                                           float* __restrict__ outv,
                                           const float* __restrict__ W,
                                           const float* __restrict__ B) {
    #pragma unroll
    for (int o4 = 0; o4 < 16; ++o4) {
        const float4 bv = *(const float4*)&B[o4 * 4];
        float ax = bv.x, ay = bv.y, az = bv.z, aw = bv.w;
        #pragma unroll
        for (int i = 0; i < K; ++i) {
            const float4 wv = *(const float4*)&W[i * 64 + o4 * 4];
            const float fv = in[i];
            ax = fmaf(fv, wv.x, ax); ay = fmaf(fv, wv.y, ay);
            az = fmaf(fv, wv.z, az); aw = fmaf(fv, wv.w, aw);
        }
        outv[o4 * 4 + 0] = fmaxf(ax, 0.f);
        outv[o4 * 4 + 1] = fmaxf(ay, 0.f);
        outv[o4 * 4 + 2] = fmaxf(az, 0.f);
        outv[o4 * 4 + 3] = fmaxf(aw, 0.f);
    }
}

// ---------------------------------------------------------------------------
// Kernel B: one block per ray. 256 threads; j-loop (NOT unrolled) gives each
// thread samples s = j*256 + t. Per-sample alpha/rgb go straight to LDS.
// Register ping-pong h1/h2; NO min-waves launch bound (round-3's ",2" made
// the allocator clamp to 128 VGPRs and spill 188 MB to scratch).
// ---------------------------------------------------------------------------
__global__ __launch_bounds__(256)
void raymarch_kernel(const float* __restrict__ ro, const float* __restrict__ rd,
                     const float* __restrict__ vd, const float* __restrict__ grid,
                     const float* __restrict__ nrm,
                     const float* __restrict__ w0, const float* __restrict__ b0,
                     const float* __restrict__ w1, const float* __restrict__ b1,
                     const float* __restrict__ w2, const float* __restrict__ b2,
                     const float* __restrict__ w3, const float* __restrict__ b3,
                     float* __restrict__ out) {
    __shared__ __align__(16) float sw0[54 * 64];
    __shared__ __align__(16) float sw1[64 * 64];
    __shared__ __align__(16) float sw2[64 * 64];
    __shared__ __align__(16) float sw3[64 * 3];
    __shared__ __align__(16) float sb0[64], sb1[64], sb2[64];
    __shared__ float sb3[4];
    __shared__ float lgl[1024];      // log(max(1-alpha,1e-10)) per sample
    __shared__ float salpha[1024];
    __shared__ float scr[1024], scg[1024], scb[1024];
    __shared__ float aux[256];
    __shared__ float red[12];

    const int t = threadIdx.x;
    const int ray = blockIdx.x;

    for (int i = t; i < 54 * 64; i += 256) sw0[i] = w0[i];
    for (int i = t; i < 64 * 64; i += 256) sw1[i] = w1[i];
    for (int i = t; i < 64 * 64; i += 256) sw2[i] = w2[i];
    for (int i = t; i < 64 * 3;  i += 256) sw3[i] = w3[i];
    if (t < 64) { sb0[t] = b0[t]; sb1[t] = b1[t]; sb2[t] = b2[t]; }
    if (t < 3) sb3[t] = b3[t];
    if (t == 3) sb3[3] = 0.f;
    __syncthreads();

    const float ox = ro[ray * 3 + 0], oy = ro[ray * 3 + 1], oz = ro[ray * 3 + 2];
    const float dx = rd[ray * 3 + 0], dyv = rd[ray * 3 + 1], dzv = rd[ray * 3 + 2];
    const float vx = vd[ray * 3 + 0], vy = vd[ray * 3 + 1], vz = vd[ray * 3 + 2];

    // ray-box entry/exit (reference semantics)
    const float ex = (dx  == 0.f) ? 1e-6f : dx;
    const float ey = (dyv == 0.f) ? 1e-6f : dyv;
    const float ez = (dzv == 0.f) ? 1e-6f : dzv;
    const float rax = (1.f - ox) / ex, rbx = (-1.f - ox) / ex;
    const float ray_ = (1.f - oy) / ey, rby = (-1.f - oy) / ey;
    const float raz = (1.f - oz) / ez, rbz = (-1.f - oz) / ez;
    float tmin = fmaxf(fmaxf(fminf(rax, rbx), fminf(ray_, rby)), fminf(raz, rbz));
    float tmax = fminf(fminf(fmaxf(rax, rbx), fmaxf(ray_, rby)), fmaxf(raz, rbz));
    tmin = fminf(fmaxf(tmin, 0.2f), 3.0f);
    tmax = fminf(fmaxf(tmax, 0.2f), 3.0f);
    const bool mask_ray = (tmax <= tmin);
    const float invn = 1.0f / sqrtf(dx * dx + dyv * dyv + dzv * dzv);

    #pragma unroll 1
    for (int j = 0; j < 4; ++j) {
        const int s = j * 256 + t;
        float alpha_s = 0.f, cr = 0.f, cg = 0.f, cb = 0.f;
        bool active = (s < N_SAMPLES) && !mask_ray;
        float px = 0.f, py = 0.f, pz = 0.f;
        if (active) {
            const float ti = tmin + STEP_T * (float)s * invn;
            px = fmaf(dx, ti, ox);
            py = fmaf(dyv, ti, oy);
            pz = fmaf(dzv, ti, oz);
            active = !(px < -1.f || px > 1.f || py < -1.f || py > 1.f ||
                       pz < -1.f || pz > 1.f);
        }
        if (active) {
            // trilinear setup; grid flat index = (ia*128 + ib)*128 + ic
            const float ga = (px + 1.f) * 63.5f;
            const float gb = (py + 1.f) * 63.5f;
            const float gc = (pz + 1.f) * 63.5f;
            const float fla = floorf(ga), flb = floorf(gb), flc = floorf(gc);
            const float fa = ga - fla, fb = gb - flb, fc = gc - flc;
            int ia0 = min(max((int)fla, 0), 127);
            int ib0 = min(max((int)flb, 0), 127);
            int ic0 = min(max((int)flc, 0), 127);
            int ia1 = min(ia0 + 1, 127);
            int ib1 = min(ib0 + 1, 127);
            int ic1 = min(ic0 + 1, 127);
            const int base00 = (ia0 * 128 + ib0) * 128;
            const int base01 = (ia0 * 128 + ib1) * 128;
            const int base10 = (ia1 * 128 + ib0) * 128;
            const int base11 = (ia1 * 128 + ib1) * 128;
            int idxs[8] = { base00 + ic0, base00 + ic1, base01 + ic0, base01 + ic1,
                            base10 + ic0, base10 + ic1, base11 + ic0, base11 + ic1 };
            const float wa0 = 1.f - fa, wb0 = 1.f - fb, wc0 = 1.f - fc;
            float w8[8] = { wa0 * wb0 * wc0, wa0 * wb0 * fc, wa0 * fb * wc0, wa0 * fb * fc,
                            fa  * wb0 * wc0, fa  * wb0 * fc, fa  * fb * wc0, fa  * fb * fc };

            float h1[64], h2[64];

            float lat0;
            {
                float lat[16];
                #pragma unroll
                for (int c = 0; c < 16; ++c) {
                    const float* gcp = grid + (size_t)c * V3;
                    float acc = 0.f;
                    #pragma unroll
                    for (int k = 0; k < 8; ++k) acc = fmaf(w8[k], gcp[idxs[k]], acc);
                    lat[c] = acc;
                }
                lat0 = lat[0];
                #pragma unroll
                for (int c = 0; c < 15; ++c) h1[c] = lat[c + 1];
            }
            float n0 = 0.f, n1 = 0.f, n2 = 0.f;
            #pragma unroll
            for (int k = 0; k < 8; ++k) {
                n0 = fmaf(w8[k], nrm[0 * V3 + idxs[k]], n0);
                n1 = fmaf(w8[k], nrm[1 * V3 + idxs[k]], n1);
                n2 = fmaf(w8[k], nrm[2 * V3 + idxs[k]], n2);
            }
            const float nl = sqrtf(n0 * n0 + n1 * n1 + n2 * n2);
            const float ninv = -1.0f / fmaxf(nl, 1e-12f);
            n0 *= ninv; n1 *= ninv; n2 *= ninv;
            const float dotv = -(vx * n0 + vy * n1 + vz * n2);
            const float rx = fmaf(2.f * dotv, n0, vx);
            const float ry = fmaf(2.f * dotv, n1, vy);
            const float rz = fmaf(2.f * dotv, n2, vz);

            // alpha = 1 - exp(-softplus(lat0 + shift) * 0.5)
            const float d0 = lat0 + ACT_SHIFT;
            const float sp = (d0 > 20.f) ? d0 : __logf(1.f + __expf(d0));
            alpha_s = 1.f - __expf(-sp * 0.5f);

            // feat = [rgb_lat(15), refdir(3), sin(18 freq-major), cos(18)]
            h1[15] = rx; h1[16] = ry; h1[17] = rz;
            float fr = 1.f;
            #pragma unroll
            for (int k = 0; k < 6; ++k) {
                h1[18 + k * 3 + 0] = __sinf(rx * fr);
                h1[18 + k * 3 + 1] = __sinf(ry * fr);
                h1[18 + k * 3 + 2] = __sinf(rz * fr);
                h1[36 + k * 3 + 0] = __cosf(rx * fr);
                h1[36 + k * 3 + 1] = __cosf(ry * fr);
                h1[36 + k * 3 + 2] = __cosf(rz * fr);
                fr *= 2.f;
            }

            layer_regs<54>(h1, h2, sw0, sb0);
            layer_regs<64>(h2, h1, sw1, sb1);
            layer_regs<64>(h1, h2, sw2, sb2);
            float a0 = sb3[0], a1 = sb3[1], a2 = sb3[2];
            #pragma unroll
            for (int i = 0; i < 64; ++i) {
                a0 = fmaf(h2[i], sw3[i * 3 + 0], a0);
                a1 = fmaf(h2[i], sw3[i * 3 + 1], a1);
                a2 = fmaf(h2[i], sw3[i * 3 + 2], a2);
            }
            cr = 1.f / (1.f + __expf(-a0));
            cg = 1.f / (1.f + __expf(-a1));
            cb = 1.f / (1.f + __expf(-a2));
        }
        // every slot s in [0,1024) gets written exactly once
        lgl[s]    = __logf(fmaxf(1.f - alpha_s, 1e-10f));
        salpha[s] = alpha_s;
        scr[s] = cr; scg[s] = cg; scb[s] = cb;
    }
    __syncthreads();

    // per-thread contiguous chunk inclusive scan (log-space transmittance)
    float c0 = lgl[4 * t + 0];
    float c1 = c0 + lgl[4 * t + 1];
    float c2 = c1 + lgl[4 * t + 2];
    float c3 = c2 + lgl[4 * t + 3];
    lgl[4 * t + 0] = c0; lgl[4 * t + 1] = c1;
    lgl[4 * t + 2] = c2; lgl[4 * t + 3] = c3;
    aux[t] = c3;
    __syncthreads();
    // Hillis-Steele inclusive scan of chunk totals
    for (int off = 1; off < 256; off <<= 1) {
        const float v = (t >= off) ? aux[t - off] : 0.f;
        __syncthreads();
        aux[t] += v;
        __syncthreads();
    }
    const float total = aux[255];

    float r0 = 0.f, r1 = 0.f, r2 = 0.f;
    #pragma unroll
    for (int j = 0; j < 4; ++j) {
        const int s = j * 256 + t;
        const float a = salpha[s];
        if (s < N_SAMPLES && a > 0.f) {
            float G;
            if (s == 0) G = 0.f;
            else {
                const int m = s - 1;
                G = lgl[m] + (((m >> 2) > 0) ? aux[(m >> 2) - 1] : 0.f);
            }
            const float T = __expf(G);    // exclusive cumprod of (1-alpha)
            const float w = a * T;
            r0 = fmaf(w, scr[s], r0);
            r1 = fmaf(w, scg[s], r1);
            r2 = fmaf(w, scb[s], r2);
        }
    }
    // block reduce (wave shuffle then LDS across 4 waves)
    #pragma unroll
    for (int off = 32; off > 0; off >>= 1) {
        r0 += __shfl_down(r0, off, 64);
        r1 += __shfl_down(r1, off, 64);
        r2 += __shfl_down(r2, off, 64);
    }
    if ((t & 63) == 0) {
        const int w = t >> 6;
        red[w * 3 + 0] = r0; red[w * 3 + 1] = r1; red[w * 3 + 2] = r2;
    }
    __syncthreads();
    if (t == 0) {
        const float Tf = __expf(total);  // alphainv_cum[:, -1] * BG (BG=1)
        out[ray * 3 + 0] = red[0] + red[3] + red[6] + red[9]  + Tf;
        out[ray * 3 + 1] = red[1] + red[4] + red[7] + red[10] + Tf;
        out[ray * 3 + 2] = red[2] + red[5] + red[8] + red[11] + Tf;
    }
}

extern "C" void kernel_launch(void* const* d_in, const int* in_sizes, int n_in,
                              void* d_out, int out_size, void* d_ws, size_t ws_size,
                              hipStream_t stream) {
    (void)in_sizes; (void)n_in; (void)out_size; (void)ws_size;
    const float* ro    = (const float*)d_in[0];
    const float* rd    = (const float*)d_in[1];
    const float* vd    = (const float*)d_in[2];
    const float* grid  = (const float*)d_in[3];
    const float* sobel = (const float*)d_in[4];
    const float* w0 = (const float*)d_in[5];
    const float* b0 = (const float*)d_in[6];
    const float* w1 = (const float*)d_in[7];
    const float* b1 = (const float*)d_in[8];
    const float* w2 = (const float*)d_in[9];
    const float* b2 = (const float*)d_in[10];
    const float* w3 = (const float*)d_in[11];
    const float* b3 = (const float*)d_in[12];
    float* nrm = (float*)d_ws;                 // 3 planes of V3 floats = 25.2 MB

    normals_conv_kernel<<<V3 / 256, 256, 0, stream>>>(grid, sobel, nrm);
    raymarch_kernel<<<N_RAYS, 256, 0, stream>>>(ro, rd, vd, grid, nrm,
                                                w0, b0, w1, b1, w2, b2, w3, b3,
                                                (float*)d_out);
}

// Round 5
// 404.641 us; speedup vs baseline: 2.3781x; 2.3781x over previous
//
#include <hip/hip_runtime.h>
#include <hip/hip_bf16.h>
#include <math.h>

// Problem constants (from reference)
#define RESV 128
#define V3 (RESV*RESV*RESV)          // 2097152 voxels per channel
#define N_RAYS 1024
#define N_SAMPLES 891                // int(257*sqrt(3)/0.5)+1
#define STEP_T 0.0078125f            // STEPSIZE * VOXEL = 0.5 * (2/128)
#define ACT_SHIFT -4.595119850134589f // log(1/(1-0.01) - 1)

typedef short bf16x8 __attribute__((ext_vector_type(8)));
typedef float f32x4 __attribute__((ext_vector_type(4)));

// fp32 -> bf16 bits, round-to-nearest-even
__device__ __forceinline__ unsigned short f2b(float x) {
    unsigned int u = __float_as_uint(x);
    unsigned int r = (u + 0x7FFFu + ((u >> 16) & 1u)) >> 16;
    return (unsigned short)r;
}

// ---------------------------------------------------------------------------
// Kernel A: 5x5x5 cross-correlation (zero pad 2), 4 z-outputs per thread via
// an 8-tap sliding window (50 loads/voxel vs 125 naive). SoA float4 stores.
// ---------------------------------------------------------------------------
__global__ __launch_bounds__(256)
void normals_conv_kernel(const float* __restrict__ grid,
                         const float* __restrict__ sobel,
                         float* __restrict__ nout) {
    __shared__ float sk[375];
    const int t = threadIdx.x;
    for (int i = t; i < 375; i += 256) sk[i] = sobel[i];
    __syncthreads();

    const int id = blockIdx.x * 256 + t;       // 0 .. V3/4-1
    const int iz4 = (id & 31) * 4;
    const int iy = (id >> 5) & 127;
    const int ix = id >> 12;

    float c0[4] = {0.f, 0.f, 0.f, 0.f};
    float c1[4] = {0.f, 0.f, 0.f, 0.f};
    float c2[4] = {0.f, 0.f, 0.f, 0.f};

    #pragma unroll
    for (int da = -2; da <= 2; ++da) {
        int a = ix + da;
        if ((unsigned)a >= 128u) continue;       // wave-uniform
        #pragma unroll
        for (int db = -2; db <= 2; ++db) {
            int b = iy + db;
            if ((unsigned)b >= 128u) continue;   // near-uniform
            const float* row = grid + (a * 128 + b) * 128;
            const float* k0  = sk + ((da + 2) * 5 + (db + 2)) * 5;
            float g[8];
            #pragma unroll
            for (int m = 0; m < 8; ++m) {
                int c = iz4 - 2 + m;
                int cc = min(max(c, 0), 127);
                float v = row[cc];
                g[m] = ((unsigned)c < 128u) ? v : 0.f;
            }
            #pragma unroll
            for (int zz = 0; zz < 4; ++zz) {
                #pragma unroll
                for (int dc = 0; dc < 5; ++dc) {
                    const float gv = g[zz + dc];
                    c0[zz] = fmaf(gv, k0[dc],       c0[zz]);
                    c1[zz] = fmaf(gv, k0[125 + dc], c1[zz]);
                    c2[zz] = fmaf(gv, k0[250 + dc], c2[zz]);
                }
            }
        }
    }
    const int vbase = (ix * 128 + iy) * 128 + iz4;
    float4 o0, o1, o2;
    float* p0 = &o0.x; float* p1 = &o1.x; float* p2 = &o2.x;
    #pragma unroll
    for (int zz = 0; zz < 4; ++zz) {
        float l   = sqrtf(c0[zz]*c0[zz] + c1[zz]*c1[zz] + c2[zz]*c2[zz]);
        float inv = -1.0f / fmaxf(l, 1e-12f);
        p0[zz] = c0[zz] * inv; p1[zz] = c1[zz] * inv; p2[zz] = c2[zz] * inv;
    }
    *(float4*)&nout[0 * (size_t)V3 + vbase] = o0;
    *(float4*)&nout[1 * (size_t)V3 + vbase] = o1;
    *(float4*)&nout[2 * (size_t)V3 + vbase] = o2;
}

// ---------------------------------------------------------------------------
// One MFMA MLP layer (64 samples x 64 outs, K=64 incl. zero padding).
// actw: per-wave activation tile [64 rows][72 bf16], in-place update (DS ops
// are in-order within a wave: all A-frag reads precede epilogue writes).
// WT: transposed weights [64 out][72 k] bf16, zero-padded. Bv: fp32 bias.
// ---------------------------------------------------------------------------
__device__ __forceinline__ void mfma_layer(unsigned short* __restrict__ actw,
                                           const unsigned short* __restrict__ WT,
                                           const float* __restrict__ Bv,
                                           int r16, int q4, int q8) {
    f32x4 acc[4][4];
    #pragma unroll
    for (int nb = 0; nb < 4; ++nb) {
        const float bv = Bv[nb * 16 + r16];
        #pragma unroll
        for (int mb = 0; mb < 4; ++mb) {
            acc[mb][nb][0] = bv; acc[mb][nb][1] = bv;
            acc[mb][nb][2] = bv; acc[mb][nb][3] = bv;
        }
    }
    #pragma unroll
    for (int ks = 0; ks < 2; ++ks) {
        bf16x8 Af[4], Bf[4];
        #pragma unroll
        for (int mb = 0; mb < 4; ++mb)
            Af[mb] = *(const bf16x8*)&actw[(mb * 16 + r16) * 72 + ks * 32 + q8];
        #pragma unroll
        for (int nb = 0; nb < 4; ++nb)
            Bf[nb] = *(const bf16x8*)&WT[(nb * 16 + r16) * 72 + ks * 32 + q8];
        #pragma unroll
        for (int mb = 0; mb < 4; ++mb) {
            #pragma unroll
            for (int nb = 0; nb < 4; ++nb)
                acc[mb][nb] = __builtin_amdgcn_mfma_f32_16x16x32_bf16(
                    Af[mb], Bf[nb], acc[mb][nb], 0, 0, 0);
        }
    }
    // relu -> bf16 -> store back in place (all reads already completed)
    #pragma unroll
    for (int mb = 0; mb < 4; ++mb) {
        #pragma unroll
        for (int nb = 0; nb < 4; ++nb) {
            #pragma unroll
            for (int r = 0; r < 4; ++r) {
                const int row = mb * 16 + q4 + r;
                actw[row * 72 + nb * 16 + r16] = f2b(fmaxf(acc[mb][nb][r], 0.f));
            }
        }
    }
}

// ---------------------------------------------------------------------------
// Kernel B: one block per ray, 256 threads, 4 waves. Wave w handles samples
// j*256 + w*64 + lane. Per-lane: gathers, feat, alpha. Per-wave: MFMA MLP
// over the 64-sample x feature tile (activations transpose via per-wave LDS).
// ---------------------------------------------------------------------------
#define WT0_OFF 0
#define WT1_OFF (64*72)
#define WT2_OFF (128*72)
#define WT3_OFF (192*72)

__global__ __launch_bounds__(256)
void raymarch_kernel(const float* __restrict__ ro, const float* __restrict__ rd,
                     const float* __restrict__ vd, const float* __restrict__ grid,
                     const float* __restrict__ nrm,
                     const float* __restrict__ w0, const float* __restrict__ b0,
                     const float* __restrict__ w1, const float* __restrict__ b1,
                     const float* __restrict__ w2, const float* __restrict__ b2,
                     const float* __restrict__ w3, const float* __restrict__ b3,
                     float* __restrict__ out) {
    __shared__ __align__(16) unsigned short sWT[208 * 72];  // WT0..WT3, bf16
    __shared__ __align__(16) unsigned short act[4 * 64 * 72];
    __shared__ float sb0f[64], sb1f[64], sb2f[64], sb3f[16];
    __shared__ float salpha[1024];
    __shared__ float scr[1024], scg[1024], scb[1024];
    __shared__ float lgl[1024];
    __shared__ float aux[256];
    __shared__ float red[12];

    const int t = threadIdx.x;
    const int ray = blockIdx.x;
    const int lane = t & 63;
    const int wave = t >> 6;
    const int r16 = lane & 15;
    const int q4 = (lane >> 4) * 4;
    const int q8 = (lane >> 4) * 8;
    unsigned short* const actw = act + wave * 64 * 72;

    // Stage weights transposed + zero-padded as bf16; biases fp32.
    for (int i = t; i < 64 * 72; i += 256) {
        int o = i / 72, k = i % 72;
        sWT[WT0_OFF + i] = f2b((k < 54) ? w0[k * 64 + o] : 0.f);
        sWT[WT1_OFF + i] = f2b((k < 64) ? w1[k * 64 + o] : 0.f);
        sWT[WT2_OFF + i] = f2b((k < 64) ? w2[k * 64 + o] : 0.f);
    }
    for (int i = t; i < 16 * 72; i += 256) {
        int n = i / 72, k = i % 72;
        sWT[WT3_OFF + i] = f2b((n < 3 && k < 64) ? w3[k * 3 + n] : 0.f);
    }
    if (t < 64) { sb0f[t] = b0[t]; sb1f[t] = b1[t]; sb2f[t] = b2[t]; }
    if (t < 16) sb3f[t] = (t < 3) ? b3[t] : 0.f;
    __syncthreads();

    const float ox = ro[ray * 3 + 0], oy = ro[ray * 3 + 1], oz = ro[ray * 3 + 2];
    const float dx = rd[ray * 3 + 0], dyv = rd[ray * 3 + 1], dzv = rd[ray * 3 + 2];
    const float vx = vd[ray * 3 + 0], vy = vd[ray * 3 + 1], vz = vd[ray * 3 + 2];

    // ray-box entry/exit (reference semantics)
    const float ex = (dx  == 0.f) ? 1e-6f : dx;
    const float ey = (dyv == 0.f) ? 1e-6f : dyv;
    const float ez = (dzv == 0.f) ? 1e-6f : dzv;
    const float rax = (1.f - ox) / ex, rbx = (-1.f - ox) / ex;
    const float ray_ = (1.f - oy) / ey, rby = (-1.f - oy) / ey;
    const float raz = (1.f - oz) / ez, rbz = (-1.f - oz) / ez;
    float tmin = fmaxf(fmaxf(fminf(rax, rbx), fminf(ray_, rby)), fminf(raz, rbz));
    float tmax = fminf(fminf(fmaxf(rax, rbx), fmaxf(ray_, rby)), fmaxf(raz, rbz));
    tmin = fminf(fmaxf(tmin, 0.2f), 3.0f);
    tmax = fminf(fmaxf(tmax, 0.2f), 3.0f);
    const bool mask_ray = (tmax <= tmin);
    const float invn = 1.0f / sqrtf(dx * dx + dyv * dyv + dzv * dzv);

    #pragma unroll 1
    for (int j = 0; j < 4; ++j) {
        const int s = j * 256 + t;         // this lane's sample
        float alpha_s = 0.f;
        bool active = (s < N_SAMPLES) && !mask_ray;
        float px = 0.f, py = 0.f, pz = 0.f;
        if (active) {
            const float ti = tmin + STEP_T * (float)s * invn;
            px = fmaf(dx, ti, ox);
            py = fmaf(dyv, ti, oy);
            pz = fmaf(dzv, ti, oz);
            active = !(px < -1.f || px > 1.f || py < -1.f || py > 1.f ||
                       pz < -1.f || pz > 1.f);
        }
        const unsigned long long wmask = __ballot(active);
        if (wmask == 0ull) {               // whole wave masked: cheap zeros
            salpha[s] = 0.f;
            scr[s] = 0.f; scg[s] = 0.f; scb[s] = 0.f;
            continue;
        }

        float feat[54];
        #pragma unroll
        for (int i = 0; i < 54; ++i) feat[i] = 0.f;

        if (active) {
            const float ga = (px + 1.f) * 63.5f;
            const float gb = (py + 1.f) * 63.5f;
            const float gc = (pz + 1.f) * 63.5f;
            const float fla = floorf(ga), flb = floorf(gb), flc = floorf(gc);
            const float fa = ga - fla, fb = gb - flb, fc = gc - flc;
            int ia0 = min(max((int)fla, 0), 127);
            int ib0 = min(max((int)flb, 0), 127);
            int ic0 = min(max((int)flc, 0), 127);
            int ia1 = min(ia0 + 1, 127);
            int ib1 = min(ib0 + 1, 127);
            int ic1 = min(ic0 + 1, 127);
            const int base00 = (ia0 * 128 + ib0) * 128;
            const int base01 = (ia0 * 128 + ib1) * 128;
            const int base10 = (ia1 * 128 + ib0) * 128;
            const int base11 = (ia1 * 128 + ib1) * 128;
            int idxs[8] = { base00 + ic0, base00 + ic1, base01 + ic0, base01 + ic1,
                            base10 + ic0, base10 + ic1, base11 + ic0, base11 + ic1 };
            const float wa0 = 1.f - fa, wb0 = 1.f - fb, wc0 = 1.f - fc;
            float w8[8] = { wa0*wb0*wc0, wa0*wb0*fc, wa0*fb*wc0, wa0*fb*fc,
                            fa*wb0*wc0,  fa*wb0*fc,  fa*fb*wc0,  fa*fb*fc };

            float lat0;
            {
                float lat[16];
                #pragma unroll
                for (int c = 0; c < 16; ++c) {
                    const float* gcp = grid + (size_t)c * V3;
                    float acc = 0.f;
                    #pragma unroll
                    for (int k = 0; k < 8; ++k) acc = fmaf(w8[k], gcp[idxs[k]], acc);
                    lat[c] = acc;
                }
                lat0 = lat[0];
                #pragma unroll
                for (int c = 0; c < 15; ++c) feat[c] = lat[c + 1];
            }
            float n0 = 0.f, n1 = 0.f, n2 = 0.f;
            #pragma unroll
            for (int k = 0; k < 8; ++k) {
                n0 = fmaf(w8[k], nrm[0 * (size_t)V3 + idxs[k]], n0);
                n1 = fmaf(w8[k], nrm[1 * (size_t)V3 + idxs[k]], n1);
                n2 = fmaf(w8[k], nrm[2 * (size_t)V3 + idxs[k]], n2);
            }
            const float nl = sqrtf(n0*n0 + n1*n1 + n2*n2);
            const float ninv = -1.0f / fmaxf(nl, 1e-12f);
            n0 *= ninv; n1 *= ninv; n2 *= ninv;
            const float dotv = -(vx * n0 + vy * n1 + vz * n2);
            const float rx = fmaf(2.f * dotv, n0, vx);
            const float ry = fmaf(2.f * dotv, n1, vy);
            const float rz = fmaf(2.f * dotv, n2, vz);

            const float d0 = lat0 + ACT_SHIFT;
            const float sp = (d0 > 20.f) ? d0 : __logf(1.f + __expf(d0));
            alpha_s = 1.f - __expf(-sp * 0.5f);

            feat[15] = rx; feat[16] = ry; feat[17] = rz;
            float fr = 1.f;
            #pragma unroll
            for (int k = 0; k < 6; ++k) {
                feat[18 + k*3 + 0] = __sinf(rx * fr);
                feat[18 + k*3 + 1] = __sinf(ry * fr);
                feat[18 + k*3 + 2] = __sinf(rz * fr);
                feat[36 + k*3 + 0] = __cosf(rx * fr);
                feat[36 + k*3 + 1] = __cosf(ry * fr);
                feat[36 + k*3 + 2] = __cosf(rz * fr);
                fr *= 2.f;
            }
        }
        salpha[s] = alpha_s;

        // ---- store feat row (bf16, cols 54..63 zeroed for clean K=64) ----
        unsigned int* arow = (unsigned int*)&act[(size_t)t * 72];
        #pragma unroll
        for (int p = 0; p < 27; ++p)
            arow[p] = (unsigned int)f2b(feat[2*p]) |
                      ((unsigned int)f2b(feat[2*p + 1]) << 16);
        #pragma unroll
        for (int p = 27; p < 32; ++p) arow[p] = 0u;

        // ---- wave-cooperative MFMA MLP (no barriers: per-wave tile) ----
        mfma_layer(actw, sWT + WT0_OFF, sb0f, r16, q4, q8);
        mfma_layer(actw, sWT + WT1_OFF, sb1f, r16, q4, q8);
        mfma_layer(actw, sWT + WT2_OFF, sb2f, r16, q4, q8);

        // head: 64 -> 3 (padded to 16 cols)
        {
            f32x4 acch[4];
            const float bv = sb3f[r16];
            #pragma unroll
            for (int mb = 0; mb < 4; ++mb) {
                acch[mb][0] = bv; acch[mb][1] = bv;
                acch[mb][2] = bv; acch[mb][3] = bv;
            }
            #pragma unroll
            for (int ks = 0; ks < 2; ++ks) {
                const bf16x8 Bh = *(const bf16x8*)&sWT[WT3_OFF + r16 * 72 + ks * 32 + q8];
                #pragma unroll
                for (int mb = 0; mb < 4; ++mb) {
                    const bf16x8 Af = *(const bf16x8*)&actw[(mb * 16 + r16) * 72 + ks * 32 + q8];
                    acch[mb] = __builtin_amdgcn_mfma_f32_16x16x32_bf16(Af, Bh, acch[mb], 0, 0, 0);
                }
            }
            if (r16 < 3) {
                float* dst = (r16 == 0) ? scr : (r16 == 1) ? scg : scb;
                const int jb = j * 256 + wave * 64;
                #pragma unroll
                for (int mb = 0; mb < 4; ++mb) {
                    #pragma unroll
                    for (int r = 0; r < 4; ++r) {
                        const int samp = mb * 16 + q4 + r;
                        dst[jb + samp] = 1.f / (1.f + __expf(-acch[mb][r]));
                    }
                }
            }
        }
    }
    __syncthreads();

    // log-space transmittance: per-thread chunk inclusive scan
    {
        const float a0 = salpha[4*t + 0], a1 = salpha[4*t + 1];
        const float a2 = salpha[4*t + 2], a3 = salpha[4*t + 3];
        float c0 = __logf(fmaxf(1.f - a0, 1e-10f));
        float c1 = c0 + __logf(fmaxf(1.f - a1, 1e-10f));
        float c2 = c1 + __logf(fmaxf(1.f - a2, 1e-10f));
        float c3 = c2 + __logf(fmaxf(1.f - a3, 1e-10f));
        lgl[4*t + 0] = c0; lgl[4*t + 1] = c1;
        lgl[4*t + 2] = c2; lgl[4*t + 3] = c3;
        aux[t] = c3;
    }
    __syncthreads();
    for (int off = 1; off < 256; off <<= 1) {
        const float v = (t >= off) ? aux[t - off] : 0.f;
        __syncthreads();
        aux[t] += v;
        __syncthreads();
    }
    const float total = aux[255];

    float r0 = 0.f, r1 = 0.f, r2 = 0.f;
    #pragma unroll
    for (int j = 0; j < 4; ++j) {
        const int s = j * 256 + t;
        const float a = salpha[s];
        if (s < N_SAMPLES && a > 0.f) {
            float G;
            if (s == 0) G = 0.f;
            else {
                const int m = s - 1;
                G = lgl[m] + (((m >> 2) > 0) ? aux[(m >> 2) - 1] : 0.f);
            }
            const float T = __expf(G);
            const float w = a * T;
            r0 = fmaf(w, scr[s], r0);
            r1 = fmaf(w, scg[s], r1);
            r2 = fmaf(w, scb[s], r2);
        }
    }
    #pragma unroll
    for (int off = 32; off > 0; off >>= 1) {
        r0 += __shfl_down(r0, off, 64);
        r1 += __shfl_down(r1, off, 64);
        r2 += __shfl_down(r2, off, 64);
    }
    if ((t & 63) == 0) {
        red[wave * 3 + 0] = r0; red[wave * 3 + 1] = r1; red[wave * 3 + 2] = r2;
    }
    __syncthreads();
    if (t == 0) {
        const float Tf = __expf(total);
        out[ray * 3 + 0] = red[0] + red[3] + red[6] + red[9]  + Tf;
        out[ray * 3 + 1] = red[1] + red[4] + red[7] + red[10] + Tf;
        out[ray * 3 + 2] = red[2] + red[5] + red[8] + red[11] + Tf;
    }
}

extern "C" void kernel_launch(void* const* d_in, const int* in_sizes, int n_in,
                              void* d_out, int out_size, void* d_ws, size_t ws_size,
                              hipStream_t stream) {
    (void)in_sizes; (void)n_in; (void)out_size; (void)ws_size;
    const float* ro    = (const float*)d_in[0];
    const float* rd    = (const float*)d_in[1];
    const float* vd    = (const float*)d_in[2];
    const float* grid  = (const float*)d_in[3];
    const float* sobel = (const float*)d_in[4];
    const float* w0 = (const float*)d_in[5];
    const float* b0 = (const float*)d_in[6];
    const float* w1 = (const float*)d_in[7];
    const float* b1 = (const float*)d_in[8];
    const float* w2 = (const float*)d_in[9];
    const float* b2 = (const float*)d_in[10];
    const float* w3 = (const float*)d_in[11];
    const float* b3 = (const float*)d_in[12];
    float* nrm = (float*)d_ws;                 // 3 planes of V3 floats = 25.2 MB

    normals_conv_kernel<<<V3 / 4 / 256, 256, 0, stream>>>(grid, sobel, nrm);
    raymarch_kernel<<<N_RAYS, 256, 0, stream>>>(ro, rd, vd, grid, nrm,
                                                w0, b0, w1, b1, w2, b2, w3, b3,
                                                (float*)d_out);
}

// Round 6
// 358.510 us; speedup vs baseline: 2.6841x; 1.1287x over previous
//
#include <hip/hip_runtime.h>
#include <hip/hip_bf16.h>
#include <hip/hip_fp16.h>
#include <math.h>

// Problem constants (from reference)
#define RESV 128
#define V3 (RESV*RESV*RESV)          // 2097152 voxels per channel
#define N_RAYS 1024
#define N_SAMPLES 891                // int(257*sqrt(3)/0.5)+1
#define STEP_T 0.0078125f            // STEPSIZE * VOXEL = 0.5 * (2/128)
#define ACT_SHIFT -4.595119850134589f // log(1/(1-0.01) - 1)

typedef short bf16x8 __attribute__((ext_vector_type(8)));
typedef float f32x4 __attribute__((ext_vector_type(4)));

// fp32 -> bf16 bits, round-to-nearest-even
__device__ __forceinline__ unsigned short f2b(float x) {
    unsigned int u = __float_as_uint(x);
    unsigned int r = (u + 0x7FFFu + ((u >> 16) & 1u)) >> 16;
    return (unsigned short)r;
}

// accumulate two bf16 channels packed in one uint into fp32 accumulators
__device__ __forceinline__ void acc2(float w, unsigned int u, float& lo, float& hi) {
    lo = fmaf(w, __uint_as_float(u << 16), lo);
    hi = fmaf(w, __uint_as_float(u & 0xffff0000u), hi);
}

// ---------------------------------------------------------------------------
// Kernel A (fused): 5x5x5 conv -> normalized normals as float4 records, and
// (if PL) repack the 16 fp32 channel-planes into voxel-interleaved bf16
// records of 16 ch = 32 B (half a cache line per corner instead of 16 lines).
// 4 z-voxels per thread, sliding window.
// ---------------------------------------------------------------------------
template <bool PL>
__global__ __launch_bounds__(256)
void normals_conv_kernel(const float* __restrict__ grid,
                         const float* __restrict__ sobel,
                         float4* __restrict__ nrm4,
                         unsigned short* __restrict__ latp) {
    __shared__ float sk[375];
    const int t = threadIdx.x;
    for (int i = t; i < 375; i += 256) sk[i] = sobel[i];
    __syncthreads();

    const int id = blockIdx.x * 256 + t;       // 0 .. V3/4-1
    const int iz4 = (id & 31) * 4;
    const int iy = (id >> 5) & 127;
    const int ix = id >> 12;

    float c0[4] = {0.f, 0.f, 0.f, 0.f};
    float c1[4] = {0.f, 0.f, 0.f, 0.f};
    float c2[4] = {0.f, 0.f, 0.f, 0.f};

    #pragma unroll
    for (int da = -2; da <= 2; ++da) {
        int a = ix + da;
        if ((unsigned)a >= 128u) continue;       // wave-uniform
        #pragma unroll
        for (int db = -2; db <= 2; ++db) {
            int b = iy + db;
            if ((unsigned)b >= 128u) continue;   // near-uniform
            const float* row = grid + (a * 128 + b) * 128;
            const float* k0  = sk + ((da + 2) * 5 + (db + 2)) * 5;
            float g[8];
            #pragma unroll
            for (int m = 0; m < 8; ++m) {
                int c = iz4 - 2 + m;
                int cc = min(max(c, 0), 127);
                float v = row[cc];
                g[m] = ((unsigned)c < 128u) ? v : 0.f;
            }
            #pragma unroll
            for (int zz = 0; zz < 4; ++zz) {
                #pragma unroll
                for (int dc = 0; dc < 5; ++dc) {
                    const float gv = g[zz + dc];
                    c0[zz] = fmaf(gv, k0[dc],       c0[zz]);
                    c1[zz] = fmaf(gv, k0[125 + dc], c1[zz]);
                    c2[zz] = fmaf(gv, k0[250 + dc], c2[zz]);
                }
            }
        }
    }
    const int vbase = (ix * 128 + iy) * 128 + iz4;
    #pragma unroll
    for (int zz = 0; zz < 4; ++zz) {
        float l   = sqrtf(c0[zz]*c0[zz] + c1[zz]*c1[zz] + c2[zz]*c2[zz]);
        float inv = -1.0f / fmaxf(l, 1e-12f);
        nrm4[vbase + zz] = make_float4(c0[zz]*inv, c1[zz]*inv, c2[zz]*inv, 0.f);
    }

    if constexpr (PL) {
        unsigned int ru[4][8];
        #pragma unroll
        for (int c = 0; c < 16; c += 2) {
            const float4 ga = *(const float4*)&grid[(size_t)c * V3 + vbase];
            const float4 gb = *(const float4*)&grid[(size_t)(c + 1) * V3 + vbase];
            const float* pa = &ga.x; const float* pb = &gb.x;
            #pragma unroll
            for (int zz = 0; zz < 4; ++zz)
                ru[zz][c >> 1] = (unsigned int)f2b(pa[zz]) |
                                 ((unsigned int)f2b(pb[zz]) << 16);
        }
        #pragma unroll
        for (int zz = 0; zz < 4; ++zz) {
            uint4* dst = (uint4*)&latp[(size_t)(vbase + zz) * 16];
            dst[0] = make_uint4(ru[zz][0], ru[zz][1], ru[zz][2], ru[zz][3]);
            dst[1] = make_uint4(ru[zz][4], ru[zz][5], ru[zz][6], ru[zz][7]);
        }
    }
}

// ---------------------------------------------------------------------------
// One MFMA MLP layer (64 samples x 64 outs, K=64 incl. zero padding).
// ---------------------------------------------------------------------------
__device__ __forceinline__ void mfma_layer(unsigned short* __restrict__ actw,
                                           const unsigned short* __restrict__ WT,
                                           const float* __restrict__ Bv,
                                           int r16, int q4, int q8) {
    f32x4 acc[4][4];
    #pragma unroll
    for (int nb = 0; nb < 4; ++nb) {
        const float bv = Bv[nb * 16 + r16];
        #pragma unroll
        for (int mb = 0; mb < 4; ++mb) {
            acc[mb][nb][0] = bv; acc[mb][nb][1] = bv;
            acc[mb][nb][2] = bv; acc[mb][nb][3] = bv;
        }
    }
    #pragma unroll
    for (int ks = 0; ks < 2; ++ks) {
        bf16x8 Af[4], Bf[4];
        #pragma unroll
        for (int mb = 0; mb < 4; ++mb)
            Af[mb] = *(const bf16x8*)&actw[(mb * 16 + r16) * 72 + ks * 32 + q8];
        #pragma unroll
        for (int nb = 0; nb < 4; ++nb)
            Bf[nb] = *(const bf16x8*)&WT[(nb * 16 + r16) * 72 + ks * 32 + q8];
        #pragma unroll
        for (int mb = 0; mb < 4; ++mb) {
            #pragma unroll
            for (int nb = 0; nb < 4; ++nb)
                acc[mb][nb] = __builtin_amdgcn_mfma_f32_16x16x32_bf16(
                    Af[mb], Bf[nb], acc[mb][nb], 0, 0, 0);
        }
    }
    #pragma unroll
    for (int mb = 0; mb < 4; ++mb) {
        #pragma unroll
        for (int nb = 0; nb < 4; ++nb) {
            #pragma unroll
            for (int r = 0; r < 4; ++r) {
                const int row = mb * 16 + q4 + r;
                actw[row * 72 + nb * 16 + r16] = f2b(fmaxf(acc[mb][nb][r], 0.f));
            }
        }
    }
}

// ---------------------------------------------------------------------------
// Kernel B: one block per ray, 4 waves. LDS total 81,008 B (<= 81,920) so
// TWO blocks/CU (round-5's 89.6 KB forced 1 block/CU, occupancy 9%).
// Colors/alpha stored fp16 (log/transmittance path stays fp32).
// ---------------------------------------------------------------------------
#define WT0_OFF 0
#define WT1_OFF (64*72)
#define WT2_OFF (128*72)
#define WT3_OFF (192*72)

template <bool PL>
__global__ __launch_bounds__(256)
void raymarch_kernel(const float* __restrict__ ro, const float* __restrict__ rd,
                     const float* __restrict__ vd, const float* __restrict__ grid,
                     const float4* __restrict__ nrm4,
                     const unsigned short* __restrict__ latp,
                     const float* __restrict__ w0, const float* __restrict__ b0,
                     const float* __restrict__ w1, const float* __restrict__ b1,
                     const float* __restrict__ w2, const float* __restrict__ b2,
                     const float* __restrict__ w3, const float* __restrict__ b3,
                     float* __restrict__ out) {
    __shared__ __align__(16) unsigned short sWT[208 * 72];  // 29,952 B
    __shared__ __align__(16) unsigned short act[4 * 64 * 72]; // 36,864 B
    __shared__ float sb0f[64], sb1f[64], sb2f[64], sb3f[16];
    __shared__ __half salpha[1024];                  // 2,048 B
    __shared__ __half scr[1024], scg[1024], scb[1024]; // 6,144 B
    __shared__ float lgl[1024];                      // 4,096 B
    __shared__ float aux[256];                       // 1,024 B
    __shared__ float red[12];

    const int t = threadIdx.x;
    const int ray = blockIdx.x;
    const int lane = t & 63;
    const int wave = t >> 6;
    const int r16 = lane & 15;
    const int q4 = (lane >> 4) * 4;
    const int q8 = (lane >> 4) * 8;
    unsigned short* const actw = act + wave * 64 * 72;

    for (int i = t; i < 64 * 72; i += 256) {
        int o = i / 72, k = i % 72;
        sWT[WT0_OFF + i] = f2b((k < 54) ? w0[k * 64 + o] : 0.f);
        sWT[WT1_OFF + i] = f2b((k < 64) ? w1[k * 64 + o] : 0.f);
        sWT[WT2_OFF + i] = f2b((k < 64) ? w2[k * 64 + o] : 0.f);
    }
    for (int i = t; i < 16 * 72; i += 256) {
        int n = i / 72, k = i % 72;
        sWT[WT3_OFF + i] = f2b((n < 3 && k < 64) ? w3[k * 3 + n] : 0.f);
    }
    if (t < 64) { sb0f[t] = b0[t]; sb1f[t] = b1[t]; sb2f[t] = b2[t]; }
    if (t < 16) sb3f[t] = (t < 3) ? b3[t] : 0.f;
    __syncthreads();

    const float ox = ro[ray * 3 + 0], oy = ro[ray * 3 + 1], oz = ro[ray * 3 + 2];
    const float dx = rd[ray * 3 + 0], dyv = rd[ray * 3 + 1], dzv = rd[ray * 3 + 2];
    const float vx = vd[ray * 3 + 0], vy = vd[ray * 3 + 1], vz = vd[ray * 3 + 2];

    const float ex = (dx  == 0.f) ? 1e-6f : dx;
    const float ey = (dyv == 0.f) ? 1e-6f : dyv;
    const float ez = (dzv == 0.f) ? 1e-6f : dzv;
    const float rax = (1.f - ox) / ex, rbx = (-1.f - ox) / ex;
    const float ray_ = (1.f - oy) / ey, rby = (-1.f - oy) / ey;
    const float raz = (1.f - oz) / ez, rbz = (-1.f - oz) / ez;
    float tmin = fmaxf(fmaxf(fminf(rax, rbx), fminf(ray_, rby)), fminf(raz, rbz));
    float tmax = fminf(fminf(fmaxf(rax, rbx), fmaxf(ray_, rby)), fmaxf(raz, rbz));
    tmin = fminf(fmaxf(tmin, 0.2f), 3.0f);
    tmax = fminf(fmaxf(tmax, 0.2f), 3.0f);
    const bool mask_ray = (tmax <= tmin);
    const float invn = 1.0f / sqrtf(dx * dx + dyv * dyv + dzv * dzv);

    #pragma unroll 1
    for (int j = 0; j < 4; ++j) {
        const int s = j * 256 + t;
        float alpha_s = 0.f;
        bool active = (s < N_SAMPLES) && !mask_ray;
        float px = 0.f, py = 0.f, pz = 0.f;
        if (active) {
            const float ti = tmin + STEP_T * (float)s * invn;
            px = fmaf(dx, ti, ox);
            py = fmaf(dyv, ti, oy);
            pz = fmaf(dzv, ti, oz);
            active = !(px < -1.f || px > 1.f || py < -1.f || py > 1.f ||
                       pz < -1.f || pz > 1.f);
        }
        const unsigned long long wmask = __ballot(active);
        if (wmask == 0ull) {
            salpha[s] = __float2half(0.f);
            lgl[s] = 0.f;
            scr[s] = __float2half(0.f); scg[s] = __float2half(0.f);
            scb[s] = __float2half(0.f);
            continue;
        }

        float feat[54];
        #pragma unroll
        for (int i = 0; i < 54; ++i) feat[i] = 0.f;

        if (active) {
            const float ga = (px + 1.f) * 63.5f;
            const float gb = (py + 1.f) * 63.5f;
            const float gc = (pz + 1.f) * 63.5f;
            const float fla = floorf(ga), flb = floorf(gb), flc = floorf(gc);
            const float fa = ga - fla, fb = gb - flb, fc = gc - flc;
            int ia0 = min(max((int)fla, 0), 127);
            int ib0 = min(max((int)flb, 0), 127);
            int ic0 = min(max((int)flc, 0), 127);
            int ia1 = min(ia0 + 1, 127);
            int ib1 = min(ib0 + 1, 127);
            int ic1 = min(ic0 + 1, 127);
            const int base00 = (ia0 * 128 + ib0) * 128;
            const int base01 = (ia0 * 128 + ib1) * 128;
            const int base10 = (ia1 * 128 + ib0) * 128;
            const int base11 = (ia1 * 128 + ib1) * 128;
            int idxs[8] = { base00 + ic0, base00 + ic1, base01 + ic0, base01 + ic1,
                            base10 + ic0, base10 + ic1, base11 + ic0, base11 + ic1 };
            const float wa0 = 1.f - fa, wb0 = 1.f - fb, wc0 = 1.f - fc;
            float w8[8] = { wa0*wb0*wc0, wa0*wb0*fc, wa0*fb*wc0, wa0*fb*fc,
                            fa*wb0*wc0,  fa*wb0*fc,  fa*fb*wc0,  fa*fb*fc };

            float lat[16];
            #pragma unroll
            for (int c = 0; c < 16; ++c) lat[c] = 0.f;
            if constexpr (PL) {
                #pragma unroll
                for (int k = 0; k < 8; ++k) {
                    const uint4* rec = (const uint4*)&latp[(size_t)idxs[k] * 16];
                    const uint4 u0 = rec[0];
                    const uint4 u1 = rec[1];
                    const float w = w8[k];
                    acc2(w, u0.x, lat[0],  lat[1]);
                    acc2(w, u0.y, lat[2],  lat[3]);
                    acc2(w, u0.z, lat[4],  lat[5]);
                    acc2(w, u0.w, lat[6],  lat[7]);
                    acc2(w, u1.x, lat[8],  lat[9]);
                    acc2(w, u1.y, lat[10], lat[11]);
                    acc2(w, u1.z, lat[12], lat[13]);
                    acc2(w, u1.w, lat[14], lat[15]);
                }
            } else {
                #pragma unroll
                for (int c = 0; c < 16; ++c) {
                    const float* gcp = grid + (size_t)c * V3;
                    float acc = 0.f;
                    #pragma unroll
                    for (int k = 0; k < 8; ++k) acc = fmaf(w8[k], gcp[idxs[k]], acc);
                    lat[c] = acc;
                }
            }
            const float lat0 = lat[0];
            #pragma unroll
            for (int c = 0; c < 15; ++c) feat[c] = lat[c + 1];

            float n0 = 0.f, n1 = 0.f, n2 = 0.f;
            #pragma unroll
            for (int k = 0; k < 8; ++k) {
                const float4 nv = nrm4[idxs[k]];
                n0 = fmaf(w8[k], nv.x, n0);
                n1 = fmaf(w8[k], nv.y, n1);
                n2 = fmaf(w8[k], nv.z, n2);
            }
            const float nl = sqrtf(n0*n0 + n1*n1 + n2*n2);
            const float ninv = -1.0f / fmaxf(nl, 1e-12f);
            n0 *= ninv; n1 *= ninv; n2 *= ninv;
            const float dotv = -(vx * n0 + vy * n1 + vz * n2);
            const float rx = fmaf(2.f * dotv, n0, vx);
            const float ry = fmaf(2.f * dotv, n1, vy);
            const float rz = fmaf(2.f * dotv, n2, vz);

            const float d0 = lat0 + ACT_SHIFT;
            const float sp = (d0 > 20.f) ? d0 : __logf(1.f + __expf(d0));
            alpha_s = 1.f - __expf(-sp * 0.5f);

            feat[15] = rx; feat[16] = ry; feat[17] = rz;
            float fr = 1.f;
            #pragma unroll
            for (int k = 0; k < 6; ++k) {
                feat[18 + k*3 + 0] = __sinf(rx * fr);
                feat[18 + k*3 + 1] = __sinf(ry * fr);
                feat[18 + k*3 + 2] = __sinf(rz * fr);
                feat[36 + k*3 + 0] = __cosf(rx * fr);
                feat[36 + k*3 + 1] = __cosf(ry * fr);
                feat[36 + k*3 + 2] = __cosf(rz * fr);
                fr *= 2.f;
            }
        }
        salpha[s] = __float2half(alpha_s);
        lgl[s] = __logf(fmaxf(1.f - alpha_s, 1e-10f));

        unsigned int* arow = (unsigned int*)&act[(size_t)t * 72];
        #pragma unroll
        for (int p = 0; p < 27; ++p)
            arow[p] = (unsigned int)f2b(feat[2*p]) |
                      ((unsigned int)f2b(feat[2*p + 1]) << 16);
        #pragma unroll
        for (int p = 27; p < 32; ++p) arow[p] = 0u;

        mfma_layer(actw, sWT + WT0_OFF, sb0f, r16, q4, q8);
        mfma_layer(actw, sWT + WT1_OFF, sb1f, r16, q4, q8);
        mfma_layer(actw, sWT + WT2_OFF, sb2f, r16, q4, q8);

        {
            f32x4 acch[4];
            const float bv = sb3f[r16];
            #pragma unroll
            for (int mb = 0; mb < 4; ++mb) {
                acch[mb][0] = bv; acch[mb][1] = bv;
                acch[mb][2] = bv; acch[mb][3] = bv;
            }
            #pragma unroll
            for (int ks = 0; ks < 2; ++ks) {
                const bf16x8 Bh = *(const bf16x8*)&sWT[WT3_OFF + r16 * 72 + ks * 32 + q8];
                #pragma unroll
                for (int mb = 0; mb < 4; ++mb) {
                    const bf16x8 Af = *(const bf16x8*)&actw[(mb * 16 + r16) * 72 + ks * 32 + q8];
                    acch[mb] = __builtin_amdgcn_mfma_f32_16x16x32_bf16(Af, Bh, acch[mb], 0, 0, 0);
                }
            }
            if (r16 < 3) {
                __half* dst = (r16 == 0) ? scr : (r16 == 1) ? scg : scb;
                const int jb = j * 256 + wave * 64;
                #pragma unroll
                for (int mb = 0; mb < 4; ++mb) {
                    #pragma unroll
                    for (int r = 0; r < 4; ++r) {
                        const int samp = mb * 16 + q4 + r;
                        dst[jb + samp] = __float2half(1.f / (1.f + __expf(-acch[mb][r])));
                    }
                }
            }
        }
    }
    __syncthreads();

    // transmittance: chunk scan of lgl + Hillis-Steele over chunk totals
    {
        float c0 = lgl[4*t + 0];
        float c1 = c0 + lgl[4*t + 1];
        float c2 = c1 + lgl[4*t + 2];
        float c3 = c2 + lgl[4*t + 3];
        lgl[4*t + 0] = c0; lgl[4*t + 1] = c1;
        lgl[4*t + 2] = c2; lgl[4*t + 3] = c3;
        aux[t] = c3;
    }
    __syncthreads();
    for (int off = 1; off < 256; off <<= 1) {
        const float v = (t >= off) ? aux[t - off] : 0.f;
        __syncthreads();
        aux[t] += v;
        __syncthreads();
    }
    const float total = aux[255];

    float r0 = 0.f, r1 = 0.f, r2 = 0.f;
    #pragma unroll
    for (int j = 0; j < 4; ++j) {
        const int s = j * 256 + t;
        const float a = __half2float(salpha[s]);
        if (s < N_SAMPLES && a > 0.f) {
            float G;
            if (s == 0) G = 0.f;
            else {
                const int m = s - 1;
                G = lgl[m] + (((m >> 2) > 0) ? aux[(m >> 2) - 1] : 0.f);
            }
            const float T = __expf(G);
            const float w = a * T;
            r0 = fmaf(w, __half2float(scr[s]), r0);
            r1 = fmaf(w, __half2float(scg[s]), r1);
            r2 = fmaf(w, __half2float(scb[s]), r2);
        }
    }
    #pragma unroll
    for (int off = 32; off > 0; off >>= 1) {
        r0 += __shfl_down(r0, off, 64);
        r1 += __shfl_down(r1, off, 64);
        r2 += __shfl_down(r2, off, 64);
    }
    if ((t & 63) == 0) {
        red[wave * 3 + 0] = r0; red[wave * 3 + 1] = r1; red[wave * 3 + 2] = r2;
    }
    __syncthreads();
    if (t == 0) {
        const float Tf = __expf(total);
        out[ray * 3 + 0] = red[0] + red[3] + red[6] + red[9]  + Tf;
        out[ray * 3 + 1] = red[1] + red[4] + red[7] + red[10] + Tf;
        out[ray * 3 + 2] = red[2] + red[5] + red[8] + red[11] + Tf;
    }
}

extern "C" void kernel_launch(void* const* d_in, const int* in_sizes, int n_in,
                              void* d_out, int out_size, void* d_ws, size_t ws_size,
                              hipStream_t stream) {
    (void)in_sizes; (void)n_in; (void)out_size;
    const float* ro    = (const float*)d_in[0];
    const float* rd    = (const float*)d_in[1];
    const float* vd    = (const float*)d_in[2];
    const float* grid  = (const float*)d_in[3];
    const float* sobel = (const float*)d_in[4];
    const float* w0 = (const float*)d_in[5];
    const float* b0 = (const float*)d_in[6];
    const float* w1 = (const float*)d_in[7];
    const float* b1 = (const float*)d_in[8];
    const float* w2 = (const float*)d_in[9];
    const float* b2 = (const float*)d_in[10];
    const float* w3 = (const float*)d_in[11];
    const float* b3 = (const float*)d_in[12];

    float4* nrm4 = (float4*)d_ws;                        // V3 * 16 B = 32 MB
    const size_t NRM_BYTES = (size_t)V3 * 16;
    const size_t LAT_BYTES = (size_t)V3 * 32;            // 64 MB
    unsigned short* latp = (unsigned short*)((char*)d_ws + NRM_BYTES);
    const bool packed = (ws_size >= NRM_BYTES + LAT_BYTES);

    if (packed) {
        normals_conv_kernel<true><<<V3 / 4 / 256, 256, 0, stream>>>(grid, sobel, nrm4, latp);
        raymarch_kernel<true><<<N_RAYS, 256, 0, stream>>>(ro, rd, vd, grid, nrm4, latp,
                                                          w0, b0, w1, b1, w2, b2, w3, b3,
                                                          (float*)d_out);
    } else {
        normals_conv_kernel<false><<<V3 / 4 / 256, 256, 0, stream>>>(grid, sobel, nrm4, latp);
        raymarch_kernel<false><<<N_RAYS, 256, 0, stream>>>(ro, rd, vd, grid, nrm4, latp,
                                                           w0, b0, w1, b1, w2, b2, w3, b3,
                                                           (float*)d_out);
    }
}